// Round 1
// baseline (297.760 us; speedup 1.0000x reference)
//
#include <hip/hip_runtime.h>

#define BATCH   4096
#define IN_DIM  2048
#define OUT_DIM 14951
#define NTHREADS 256

// out[b, j] = -scale * FWHT2048(x_row_normalized)[j & 2047] + bias[j]
// FWHT because H[i,j] = (-1)^popc(i&j) with i<2048 only sees j&2047, and
// x @ H2048 (Sylvester, natural order) per-row == length-2048 FWHT.
__global__ __launch_bounds__(NTHREADS) void HadamardClassifier_44487271252814_kernel(
    const float* __restrict__ x,
    const float* __restrict__ scale,
    const float* __restrict__ bias,
    float* __restrict__ out)
{
    __shared__ float y[IN_DIM];
    __shared__ float wsum[NTHREADS / 64];

    const int tid = threadIdx.x;
    const int b   = blockIdx.x;
    const float* xrow = x + (size_t)b * IN_DIM;

    // Each thread owns 8 consecutive elements [8*tid, 8*tid+8).
    float4 v0 = reinterpret_cast<const float4*>(xrow)[2 * tid];
    float4 v1 = reinterpret_cast<const float4*>(xrow)[2 * tid + 1];

    // --- sum of squares (for L2 normalization; applied in epilogue since FWHT is linear)
    float ss = v0.x * v0.x + v0.y * v0.y + v0.z * v0.z + v0.w * v0.w
             + v1.x * v1.x + v1.y * v1.y + v1.z * v1.z + v1.w * v1.w;
    #pragma unroll
    for (int o = 32; o > 0; o >>= 1) ss += __shfl_down(ss, o, 64);
    if ((tid & 63) == 0) wsum[tid >> 6] = ss;

    // --- FWHT stages h=1,2,4 in registers (within the owned aligned 8-block)
    float a0 = v0.x, a1 = v0.y, a2 = v0.z, a3 = v0.w;
    float a4 = v1.x, a5 = v1.y, a6 = v1.z, a7 = v1.w;
    // h = 1
    float b0 = a0 + a1, b1 = a0 - a1, b2 = a2 + a3, b3 = a2 - a3;
    float b4 = a4 + a5, b5 = a4 - a5, b6 = a6 + a7, b7 = a6 - a7;
    // h = 2
    float c0 = b0 + b2, c1 = b1 + b3, c2 = b0 - b2, c3 = b1 - b3;
    float c4 = b4 + b6, c5 = b5 + b7, c6 = b4 - b6, c7 = b5 - b7;
    // h = 4
    a0 = c0 + c4; a1 = c1 + c5; a2 = c2 + c6; a3 = c3 + c7;
    a4 = c0 - c4; a5 = c1 - c5; a6 = c2 - c6; a7 = c3 - c7;

    const int base = 8 * tid;
    y[base + 0] = a0; y[base + 1] = a1; y[base + 2] = a2; y[base + 3] = a3;
    y[base + 4] = a4; y[base + 5] = a5; y[base + 6] = a6; y[base + 7] = a7;
    __syncthreads();

    // --- FWHT stages h=8..1024 in LDS (disjoint butterfly pairs per stage)
    #pragma unroll
    for (int h = 8; h < IN_DIM; h <<= 1) {
        #pragma unroll
        for (int r = 0; r < IN_DIM / 2 / NTHREADS; ++r) {
            int idx = tid + r * NTHREADS;                       // 0..1023
            int i = ((idx & ~(h - 1)) << 1) | (idx & (h - 1));  // h-bit cleared
            float u = y[i];
            float w = y[i + h];
            y[i]     = u + w;
            y[i + h] = u - w;
        }
        __syncthreads();
    }

    // --- epilogue: out[b, j] = s * y[j & 2047] + bias[j]
    float total = wsum[0] + wsum[1] + wsum[2] + wsum[3];
    float inv = rsqrtf(fmaxf(total, 1e-12f));
    float s = -scale[0] * inv;

    float* orow = out + (size_t)b * OUT_DIM;
    for (int j = tid; j < OUT_DIM; j += NTHREADS) {
        orow[j] = s * y[j & (IN_DIM - 1)] + bias[j];
    }
}

extern "C" void kernel_launch(void* const* d_in, const int* in_sizes, int n_in,
                              void* d_out, int out_size, void* d_ws, size_t ws_size,
                              hipStream_t stream) {
    const float* x     = (const float*)d_in[0];
    const float* scale = (const float*)d_in[1];
    const float* bias  = (const float*)d_in[2];
    float* out = (float*)d_out;

    hipLaunchKernelGGL(HadamardClassifier_44487271252814_kernel,
                       dim3(BATCH), dim3(NTHREADS), 0, stream,
                       x, scale, bias, out);
}

// Round 2
// 288.394 us; speedup vs baseline: 1.0325x; 1.0325x over previous
//
#include <hip/hip_runtime.h>

#define BATCH   4096
#define IN_DIM  2048
#define OUT_DIM 14951
#define ROWS    4              // rows per block; 4*14951 floats = 59804, /4 = 14951 float4s, 16B-aligned base
#define NT      512            // 8 waves; 128 threads per row
#define STRIDE  2052           // LDS row stride (floats), %4==0 keeps b128 ops aligned
#define EPS     1e-12f

// out[b, j] = -scale/||x_b|| * FWHT2048(x_b)[j & 2047] + bias[j]
// H[i,j] = (-1)^popc(i&j), i < 2048 => column j == column (j & 2047) of the
// 2048x2048 Sylvester matrix; x @ H2048 per row == length-2048 natural-order FWHT.
__global__ __launch_bounds__(NT, 8) void HadamardClassifier_44487271252814_kernel(
    const float* __restrict__ x,
    const float* __restrict__ scale,
    const float* __restrict__ bias,
    float* __restrict__ out)
{
    __shared__ float y[ROWS * STRIDE];     // 32,832 B
    __shared__ float rss[ROWS * 2];        // 2 wave partial sums per row
    __shared__ float srow[ROWS];           // per-row -scale/||x||

    const int tid = threadIdx.x;
    const int r   = tid >> 7;              // row within block (0..3); waves never straddle rows
    const int t   = tid & 127;             // thread within row
    const int b0  = blockIdx.x * ROWS;

    // ---- load 16 consecutive elements [16t, 16t+16) of row r: coalesced 16B/lane
    const float4* xv = reinterpret_cast<const float4*>(x + (size_t)(b0 + r) * IN_DIM) + 4 * t;
    float4 v0 = xv[0], v1 = xv[1], v2 = xv[2], v3 = xv[3];
    float a[16] = { v0.x, v0.y, v0.z, v0.w, v1.x, v1.y, v1.z, v1.w,
                    v2.x, v2.y, v2.z, v2.w, v3.x, v3.y, v3.z, v3.w };

    // ---- sum of squares for L2 norm (linear op: fold into epilogue scale)
    float ss = 0.f;
    #pragma unroll
    for (int k = 0; k < 16; ++k) ss += a[k] * a[k];
    #pragma unroll
    for (int o = 32; o > 0; o >>= 1) ss += __shfl_down(ss, o, 64);
    if ((tid & 63) == 0) rss[tid >> 6] = ss;   // waves 2r, 2r+1 belong to row r

    // ---- FWHT stages h=1,2,4,8 in registers (16 owned consecutive elements)
    #pragma unroll
    for (int h = 1; h < 16; h <<= 1) {
        #pragma unroll
        for (int g = 0; g < 16; g += 2 * h) {
            #pragma unroll
            for (int k = 0; k < h; ++k) {
                float u = a[g + k], w = a[g + k + h];
                a[g + k]     = u + w;
                a[g + k + h] = u - w;
            }
        }
    }

    float* yr = y + r * STRIDE;
    #pragma unroll
    for (int k = 0; k < 4; ++k) {   // aligned b128 writes
        *reinterpret_cast<float4*>(&yr[16 * t + 4 * k]) =
            make_float4(a[4 * k], a[4 * k + 1], a[4 * k + 2], a[4 * k + 3]);
    }
    __syncthreads();

    if (tid < ROWS)
        srow[tid] = -scale[0] * rsqrtf(fmaxf(rss[2 * tid] + rss[2 * tid + 1], EPS));
    // (visible after the next stage barrier)

    // ---- FWHT stages h=16..1024 in LDS, vectorized float4 butterflies
    #pragma unroll
    for (int h = 16; h < IN_DIM; h <<= 1) {
        #pragma unroll
        for (int q = 0; q < 2; ++q) {
            int idx = 4 * (t + 128 * q);                          // multiple of 4
            int i = ((idx & ~(h - 1)) << 1) | (idx & (h - 1));    // 4-aligned for h>=16
            float4 u = *reinterpret_cast<float4*>(&yr[i]);
            float4 w = *reinterpret_cast<float4*>(&yr[i + h]);
            float4 su, sw;
            su.x = u.x + w.x; su.y = u.y + w.y; su.z = u.z + w.z; su.w = u.w + w.w;
            sw.x = u.x - w.x; sw.y = u.y - w.y; sw.z = u.z - w.z; sw.w = u.w - w.w;
            *reinterpret_cast<float4*>(&yr[i])     = su;
            *reinterpret_cast<float4*>(&yr[i + h]) = sw;
        }
        __syncthreads();
    }

    // ---- epilogue: flat 4-row output span, aligned float4 stores
    // block output base: b0*OUT_DIM floats; b0 % 4 == 0 -> 16B aligned; 59804 % 4 == 0
    float4* obase = reinterpret_cast<float4*>(out + (size_t)b0 * OUT_DIM);
    const int NF4 = (ROWS * OUT_DIM) / 4;   // 14951

    for (int f4 = tid; f4 < NF4; f4 += NT) {
        int e  = f4 << 2;
        int rr = (e >= OUT_DIM) + (e >= 2 * OUT_DIM) + (e >= 3 * OUT_DIM);
        int j  = e - rr * OUT_DIM;
        float4 o;
        if (j + 3 < OUT_DIM) {                 // no row straddle (all but 3 vecs/block)
            float sv = srow[rr];
            const float* yq = y + rr * STRIDE;
            int m = j & (IN_DIM - 1);
            float y0 = yq[m];
            float y1 = yq[(m + 1) & (IN_DIM - 1)];
            float y2 = yq[(m + 2) & (IN_DIM - 1)];
            float y3 = yq[(m + 3) & (IN_DIM - 1)];
            o.x = fmaf(sv, y0, bias[j]);
            o.y = fmaf(sv, y1, bias[j + 1]);
            o.z = fmaf(sv, y2, bias[j + 2]);
            o.w = fmaf(sv, y3, bias[j + 3]);
        } else {                               // row boundary inside the vec4
            float tmp[4];
            #pragma unroll
            for (int c = 0; c < 4; ++c) {
                int ee = e + c;
                int rc = (ee >= OUT_DIM) + (ee >= 2 * OUT_DIM) + (ee >= 3 * OUT_DIM);
                int jc = ee - rc * OUT_DIM;
                tmp[c] = fmaf(srow[rc], y[rc * STRIDE + (jc & (IN_DIM - 1))], bias[jc]);
            }
            o = make_float4(tmp[0], tmp[1], tmp[2], tmp[3]);
        }
        obase[f4] = o;
    }
}

extern "C" void kernel_launch(void* const* d_in, const int* in_sizes, int n_in,
                              void* d_out, int out_size, void* d_ws, size_t ws_size,
                              hipStream_t stream) {
    const float* x     = (const float*)d_in[0];
    const float* scale = (const float*)d_in[1];
    const float* bias  = (const float*)d_in[2];
    float* out = (float*)d_out;

    hipLaunchKernelGGL(HadamardClassifier_44487271252814_kernel,
                       dim3(BATCH / ROWS), dim3(NT), 0, stream,
                       x, scale, bias, out);
}